// Round 5
// baseline (386.193 us; speedup 1.0000x reference)
//
#include <hip/hip_runtime.h>
#include <stdint.h>

typedef float  f32x4   __attribute__((ext_vector_type(4)));
typedef float  float4v __attribute__((ext_vector_type(4)));
typedef short  short4v __attribute__((ext_vector_type(4)));
typedef short  short8v __attribute__((ext_vector_type(8)));
typedef __bf16 bf16x8  __attribute__((ext_vector_type(8)));

static __device__ __forceinline__ short f2bf(float f) {
  unsigned u = __builtin_bit_cast(unsigned, f);
  u += 0x7FFFu + ((u >> 16) & 1u);
  return (short)(u >> 16);
}

static __device__ __forceinline__ f32x4 mfma16(short8v a, short8v b, f32x4 c) {
  return __builtin_amdgcn_mfma_f32_16x16x32_bf16(
      __builtin_bit_cast(bf16x8, a), __builtin_bit_cast(bf16x8, b), c, 0, 0, 0);
}

static __device__ __forceinline__ short8v cat44(short4v a, short4v b) {
  short8v r;
  r[0] = a[0]; r[1] = a[1]; r[2] = a[2]; r[3] = a[3];
  r[4] = b[0]; r[5] = b[1]; r[6] = b[2]; r[7] = b[3];
  return r;
}

// Load 8 consecutive f32 from global, convert to bf16 fragment in-register.
static __device__ __forceinline__ short8v ldx8(const float* __restrict__ p) {
  float4v f0 = *(const float4v*)p;
  float4v f1 = *(const float4v*)(p + 4);
  short8v s;
#pragma unroll
  for (int r = 0; r < 4; ++r) { s[r] = f2bf(f0[r]); s[4 + r] = f2bf(f1[r]); }
  return s;
}

// Prelude A: convert qkv_w (384x128) and proj_w (128x128) f32 -> bf16.
__global__ void cvt_weights_kernel(const float* __restrict__ qkv_w,
                                   const float* __restrict__ proj_w,
                                   short* __restrict__ wq, short* __restrict__ wp) {
  int i = blockIdx.x * 256 + threadIdx.x;   // grid = 192 blocks -> 49152
  wq[i] = f2bf(qkv_w[i]);
  if (i < 16384) wp[i] = f2bf(proj_w[i]);
}

// Prelude B: combined bias+mask table laid out as the MFMA S-fragment:
// cmb[w(64)][h(4)][qt(4)][i(4)][lane(64)][r(4)] f32  (4 MB)
// key = i*16 + (lane>>4)*4 + r ; q = qt*16 + (lane&15)
__global__ void build_cmb_kernel(const float* __restrict__ mask,
                                 const float* __restrict__ bias_table,
                                 float* __restrict__ cmb) {
  int id   = blockIdx.x * 256 + threadIdx.x;   // grid = 1024 blocks -> 262144
  int lane = id & 63;
  int i    = (id >> 6) & 3;
  int qt   = (id >> 8) & 3;
  int h    = (id >> 10) & 3;
  int w    = id >> 12;
  int q     = qt * 16 + (lane & 15);
  int kbase = i * 16 + ((lane >> 4) << 2);
  f32x4 v;
#pragma unroll
  for (int r = 0; r < 4; ++r) {
    int key = kbase + r;
    float val;
    if (key >= 49) {
      val = -1e30f;
    } else if (q >= 49) {
      val = 0.f;
    } else {
      int qi = q / 7, qj = q - qi * 7;
      int ki = key / 7, kj = key - ki * 7;
      int ridx = (qi - ki + 6) * 13 + (qj - kj + 6);
      val = bias_table[ridx * 4 + h] + mask[w * 2401 + q * 49 + key];
    }
    v[r] = val;
  }
  ((f32x4*)cmb)[id] = v;
}

// One block = one window (49 tokens padded to 64). 512 threads = 8 waves.
// wave (g,h): g = token half, h = head. A-fragments loaded straight from
// global x (rows clamped to 48; masked keys / discarded rows make this safe).
// LDS 35 KiB -> 4 blocks/CU at VGPR<=64:
//   [0,9216)       ksm [4][64][36] k  -> later aom [64][136] (8704 shorts)
//   [9216,17920)   vtm [4][32][68] v^T: row = h*32+d, col = token
__global__ __launch_bounds__(512, 8)
void win_attn_kernel(const float* __restrict__ x,
                     const float* __restrict__ qkv_b,
                     const float* __restrict__ proj_b,
                     const short* __restrict__ wq,
                     const short* __restrict__ wp,
                     const float* __restrict__ cmb,
                     float* __restrict__ out) {
  __shared__ __align__(16) short smem[17920];
  short* ksm = smem;
  short* vtm = smem + 9216;
  short* aom = smem;     // alias over ksm (dead after kfr loads + barrier)

  const int b    = blockIdx.x;
  const int tid  = threadIdx.x;
  const int lane = tid & 63;
  const int wv   = tid >> 6;
  const int h    = wv & 3;
  const int g    = wv >> 2;
  const int l15  = lane & 15;
  const int lhi  = lane >> 4;

  const float* xw = x + (long)b * (49 * 128);
  const int r0  = g * 32 + l15;
  const int rc0 = r0 > 48 ? 48 : r0;
  const int r1  = r0 + 16;
  const int rc1 = r1 > 48 ? 48 : r1;
  const int cb  = lhi * 8;

  // ---- Phase 1a: Q,K projection, swapped (acc rows = w-col, cols = token).
  short8v qfr[2];
  {
    f32x4 qk[2][2][2];   // [mat][nt][jt]
#pragma unroll
    for (int mat = 0; mat < 2; ++mat)
#pragma unroll
      for (int nt = 0; nt < 2; ++nt) {
        const f32x4 bias4 = *(const f32x4*)&qkv_b[mat * 128 + h * 32 + nt * 16 + lhi * 4];
        qk[mat][nt][0] = bias4;
        qk[mat][nt][1] = bias4;
      }
#pragma unroll
    for (int ks = 0; ks < 4; ++ks) {
      const short8v a0 = ldx8(xw + rc0 * 128 + ks * 32 + cb);
      const short8v a1 = ldx8(xw + rc1 * 128 + ks * 32 + cb);
#pragma unroll
      for (int mat = 0; mat < 2; ++mat)
#pragma unroll
        for (int nt = 0; nt < 2; ++nt) {
          const short8v bfr =
              *(const short8v*)&wq[(mat * 128 + h * 32 + nt * 16 + l15) * 128 + ks * 32 + cb];
          qk[mat][nt][0] = mfma16(bfr, a0, qk[mat][nt][0]);
          qk[mat][nt][1] = mfma16(bfr, a1, qk[mat][nt][1]);
        }
    }
    const float scale = 0.1767766952966369f;  // 32^-0.5
#pragma unroll
    for (int jt = 0; jt < 2; ++jt) {
      short8v qv;
#pragma unroll
      for (int nt = 0; nt < 2; ++nt)
#pragma unroll
        for (int r = 0; r < 4; ++r)
          qv[nt * 4 + r] = f2bf(qk[0][nt][jt][r] * scale);
      qfr[jt] = qv;
    }
#pragma unroll
    for (int jt = 0; jt < 2; ++jt)
#pragma unroll
      for (int nt = 0; nt < 2; ++nt)
#pragma unroll
        for (int r = 0; r < 4; ++r)
          ksm[h * 2304 + (g * 32 + jt * 16 + l15) * 36 + nt * 16 + lhi * 4 + r] =
              f2bf(qk[1][nt][jt][r]);
  }

  // ---- Phase 1b: V projection (normal orientation), store transposed.
  {
    f32x4 av[2][2];      // [nt][mt]
#pragma unroll
    for (int nt = 0; nt < 2; ++nt) {
      const float vb = qkv_b[256 + h * 32 + nt * 16 + l15];
      av[nt][0] = f32x4{vb, vb, vb, vb};
      av[nt][1] = av[nt][0];
    }
#pragma unroll
    for (int ks = 0; ks < 4; ++ks) {
      const short8v a0 = ldx8(xw + rc0 * 128 + ks * 32 + cb);
      const short8v a1 = ldx8(xw + rc1 * 128 + ks * 32 + cb);
#pragma unroll
      for (int nt = 0; nt < 2; ++nt) {
        const short8v bfr =
            *(const short8v*)&wq[(256 + h * 32 + nt * 16 + l15) * 128 + ks * 32 + cb];
        av[nt][0] = mfma16(a0, bfr, av[nt][0]);
        av[nt][1] = mfma16(a1, bfr, av[nt][1]);
      }
    }
#pragma unroll
    for (int nt = 0; nt < 2; ++nt)
#pragma unroll
      for (int mt = 0; mt < 2; ++mt) {
        short4v p;
#pragma unroll
        for (int r = 0; r < 4; ++r) p[r] = f2bf(av[nt][mt][r]);
        *(short4v*)&vtm[(h * 32 + nt * 16 + l15) * 68 + g * 32 + mt * 16 + lhi * 4] = p;
      }
  }
  __syncthreads();

  // ---- Phase 2: S = mfma(K,Q) + cmb; softmax in-lane; swapped PV from regs
  {
    short8v kfr[4];
#pragma unroll
    for (int i = 0; i < 4; ++i) {
      const int ka = h * 2304 + (i * 16 + l15) * 36 + lhi * 4;
      kfr[i] = cat44(*(const short4v*)&ksm[ka], *(const short4v*)&ksm[ka + 16]);
    }
    __syncthreads();   // ksm fully consumed; aom may overwrite it below

    const f32x4* cmb4 = (const f32x4*)cmb;
    const long cbase = (long)(b & 63) * 4096 + h * 1024 + g * 512 + lane;

#pragma unroll
    for (int jt = 0; jt < 2; ++jt) {
      f32x4 s[4];
#pragma unroll
      for (int i = 0; i < 4; ++i)
        s[i] = mfma16(kfr[i], qfr[jt], cmb4[cbase + jt * 256 + i * 64]);

      float mx = s[0][0];
#pragma unroll
      for (int i = 0; i < 4; ++i)
#pragma unroll
        for (int r = 0; r < 4; ++r) mx = fmaxf(mx, s[i][r]);
      mx = fmaxf(mx, __shfl_xor(mx, 16));
      mx = fmaxf(mx, __shfl_xor(mx, 32));
      float sum = 0.f;
#pragma unroll
      for (int i = 0; i < 4; ++i)
#pragma unroll
        for (int r = 0; r < 4; ++r) {
          float e = __expf(s[i][r] - mx);
          s[i][r] = e;
          sum += e;
        }
      sum += __shfl_xor(sum, 16);
      sum += __shfl_xor(sum, 32);
      const float inv = 1.f / sum;

      short8v pb[2];
#pragma unroll
      for (int ks = 0; ks < 2; ++ks) {
        short8v pv;
#pragma unroll
        for (int e = 0; e < 4; ++e) pv[e]     = f2bf(s[2 * ks][e] * inv);
#pragma unroll
        for (int e = 0; e < 4; ++e) pv[4 + e] = f2bf(s[2 * ks + 1][e] * inv);
        pb[ks] = pv;
      }

#pragma unroll
      for (int dt = 0; dt < 2; ++dt) {
        f32x4 o = {0.f, 0.f, 0.f, 0.f};
#pragma unroll
        for (int ks = 0; ks < 2; ++ks) {
          const int va = (h * 32 + dt * 16 + l15) * 68 + ks * 32 + lhi * 4;
          short8v vfr = cat44(*(const short4v*)&vtm[va], *(const short4v*)&vtm[va + 16]);
          o = mfma16(vfr, pb[ks], o);
        }
        short4v p;
#pragma unroll
        for (int r = 0; r < 4; ++r) p[r] = f2bf(o[r]);
        *(short4v*)&aom[(g * 32 + jt * 16 + l15) * 136 + h * 32 + dt * 16 + lhi * 4] = p;
      }
    }
  }
  __syncthreads();

  // ---- Phase 3: output projection Y = AO @ proj_w^T + proj_b (ks-outer)
  {
    f32x4 po[2][2];      // [nt][mt]
#pragma unroll
    for (int nt = 0; nt < 2; ++nt) {
      const float pbv = proj_b[h * 32 + nt * 16 + l15];
      po[nt][0] = f32x4{pbv, pbv, pbv, pbv};
      po[nt][1] = po[nt][0];
    }
#pragma unroll
    for (int ks = 0; ks < 4; ++ks) {
      const short8v p0 = *(const short8v*)&aom[(g * 32 + l15) * 136 + ks * 32 + cb];
      const short8v p1 = *(const short8v*)&aom[(g * 32 + 16 + l15) * 136 + ks * 32 + cb];
#pragma unroll
      for (int nt = 0; nt < 2; ++nt) {
        const short8v wfr =
            *(const short8v*)&wp[(h * 32 + nt * 16 + l15) * 128 + ks * 32 + cb];
        po[nt][0] = mfma16(p0, wfr, po[nt][0]);
        po[nt][1] = mfma16(p1, wfr, po[nt][1]);
      }
    }
    float* outw = out + (long)b * (49 * 128);
#pragma unroll
    for (int nt = 0; nt < 2; ++nt) {
      const int ncol = h * 32 + nt * 16 + l15;
#pragma unroll
      for (int r = 0; r < 4; ++r) {
        const int m0 = g * 32 + lhi * 4 + r;
        if (m0 < 49) outw[m0 * 128 + ncol] = po[nt][0][r];
        const int m1 = m0 + 16;
        if (m1 < 49) outw[m1 * 128 + ncol] = po[nt][1][r];
      }
    }
  }
}

extern "C" void kernel_launch(void* const* d_in, const int* in_sizes, int n_in,
                              void* d_out, int out_size, void* d_ws, size_t ws_size,
                              hipStream_t stream) {
  const float* x          = (const float*)d_in[0];
  const float* mask       = (const float*)d_in[1];
  const float* qkv_w      = (const float*)d_in[2];
  const float* qkv_b      = (const float*)d_in[3];
  const float* proj_w     = (const float*)d_in[4];
  const float* proj_b     = (const float*)d_in[5];
  const float* bias_table = (const float*)d_in[6];

  short* wq  = (short*)d_ws;                         // 384*128 bf16 (98304 B)
  short* wp  = wq + 49152;                           // 128*128 bf16 (32768 B)
  float* cmb = (float*)((char*)d_ws + 131072);       // 4 MB combined bias+mask

  cvt_weights_kernel<<<dim3(192), dim3(256), 0, stream>>>(qkv_w, proj_w, wq, wp);
  build_cmb_kernel<<<dim3(1024), dim3(256), 0, stream>>>(mask, bias_table, cmb);
  win_attn_kernel<<<dim3(4096), dim3(512), 0, stream>>>(
      x, qkv_b, proj_b, wq, wp, cmb, (float*)d_out);
}

// Round 6
// 168.441 us; speedup vs baseline: 2.2928x; 2.2928x over previous
//
#include <hip/hip_runtime.h>
#include <stdint.h>

typedef float  f32x4   __attribute__((ext_vector_type(4)));
typedef float  float4v __attribute__((ext_vector_type(4)));
typedef short  short4v __attribute__((ext_vector_type(4)));
typedef short  short8v __attribute__((ext_vector_type(8)));
typedef __bf16 bf16x8  __attribute__((ext_vector_type(8)));

static __device__ __forceinline__ short f2bf(float f) {
  unsigned u = __builtin_bit_cast(unsigned, f);
  u += 0x7FFFu + ((u >> 16) & 1u);
  return (short)(u >> 16);
}

static __device__ __forceinline__ f32x4 mfma16(short8v a, short8v b, f32x4 c) {
  return __builtin_amdgcn_mfma_f32_16x16x32_bf16(
      __builtin_bit_cast(bf16x8, a), __builtin_bit_cast(bf16x8, b), c, 0, 0, 0);
}

static __device__ __forceinline__ short8v cat44(short4v a, short4v b) {
  short8v r;
  r[0] = a[0]; r[1] = a[1]; r[2] = a[2]; r[3] = a[3];
  r[4] = b[0]; r[5] = b[1]; r[6] = b[2]; r[7] = b[3];
  return r;
}

// Prelude A: convert qkv_w (384x128) and proj_w (128x128) f32 -> bf16.
__global__ void cvt_weights_kernel(const float* __restrict__ qkv_w,
                                   const float* __restrict__ proj_w,
                                   short* __restrict__ wq, short* __restrict__ wp) {
  int i = blockIdx.x * 256 + threadIdx.x;   // grid = 192 blocks -> 49152
  wq[i] = f2bf(qkv_w[i]);
  if (i < 16384) wp[i] = f2bf(proj_w[i]);
}

// Prelude B: combined bias+mask table laid out as the MFMA S-fragment:
// cmb[w(64)][h(4)][qt(4)][i(4)][lane(64)][r(4)] f32  (4 MB)
// key = i*16 + (lane>>4)*4 + r ; q = qt*16 + (lane&15)
__global__ void build_cmb_kernel(const float* __restrict__ mask,
                                 const float* __restrict__ bias_table,
                                 float* __restrict__ cmb) {
  int id   = blockIdx.x * 256 + threadIdx.x;   // grid = 1024 blocks -> 262144
  int lane = id & 63;
  int i    = (id >> 6) & 3;
  int qt   = (id >> 8) & 3;
  int h    = (id >> 10) & 3;
  int w    = id >> 12;
  int q     = qt * 16 + (lane & 15);
  int kbase = i * 16 + ((lane >> 4) << 2);
  f32x4 v;
#pragma unroll
  for (int r = 0; r < 4; ++r) {
    int key = kbase + r;
    float val;
    if (key >= 49) {
      val = -1e30f;
    } else if (q >= 49) {
      val = 0.f;
    } else {
      int qi = q / 7, qj = q - qi * 7;
      int ki = key / 7, kj = key - ki * 7;
      int ridx = (qi - ki + 6) * 13 + (qj - kj + 6);
      val = bias_table[ridx * 4 + h] + mask[w * 2401 + q * 49 + key];
    }
    v[r] = val;
  }
  ((f32x4*)cmb)[id] = v;
}

// One block = one window (49 tokens padded to 64). 512 threads = 8 waves.
// wave (g,h): g = token half, h = head.
// LDS 35 KiB via lifetime aliasing -> 4 blocks/CU at VGPR<=64:
//   [0,8704)       xb [64][136] x tile  -> later vtm [4][32][68] (WAR barrier)
//   [8704,17920)   ksm [4][64][36] k    -> later aom [64][136]   (after kfr)
__global__ __launch_bounds__(512, 8)
void win_attn_kernel(const float* __restrict__ x,
                     const float* __restrict__ qkv_b,
                     const float* __restrict__ proj_b,
                     const short* __restrict__ wq,
                     const short* __restrict__ wp,
                     const float* __restrict__ cmb,
                     float* __restrict__ out) {
  __shared__ __align__(16) short smem[17920];
  short* xb  = smem;            // [64][136], phases 0-1
  short* vtm = smem;            // ALIAS xb: [4][32][68], phase 1b+
  short* ksm = smem + 8704;     // [4][64][36]
  short* aom = smem + 8704;     // ALIAS ksm: [64][136], phase 2+

  const int b    = blockIdx.x;
  const int tid  = threadIdx.x;
  const int lane = tid & 63;
  const int wv   = tid >> 6;
  const int h    = wv & 3;
  const int g    = wv >> 2;
  const int l15  = lane & 15;
  const int lhi  = lane >> 4;
  const int cb   = lhi * 8;

  // ---- Phase 0: stage x -> bf16 LDS, zero pad rows 49..63
  {
    short4v z = {0, 0, 0, 0};
    for (int idx = tid; idx < 510; idx += 512)
      *(short4v*)&xb[49 * 136 + idx * 4] = z;
    const float* xw = x + (long)b * (49 * 128);
    for (int idx = tid; idx < 1568; idx += 512) {
      int m  = idx >> 5;
      int c0 = (idx & 31) << 2;
      float4v v = *(const float4v*)&xw[m * 128 + c0];
      short4v s;
      s[0] = f2bf(v[0]); s[1] = f2bf(v[1]); s[2] = f2bf(v[2]); s[3] = f2bf(v[3]);
      *(short4v*)&xb[m * 136 + c0] = s;
    }
  }
  __syncthreads();

  // ---- Phase 1a: Q,K projection, swapped (acc rows = w-col, cols = token).
  // ks-outer; A-fragments reloaded from xb each iteration (keeps VGPR ~48).
  short8v qfr[2];
  {
    f32x4 qk[2][2][2];   // [mat][nt][jt]
#pragma unroll
    for (int mat = 0; mat < 2; ++mat)
#pragma unroll
      for (int nt = 0; nt < 2; ++nt) {
        const f32x4 bias4 = *(const f32x4*)&qkv_b[mat * 128 + h * 32 + nt * 16 + lhi * 4];
        qk[mat][nt][0] = bias4;
        qk[mat][nt][1] = bias4;
      }
#pragma unroll
    for (int ks = 0; ks < 4; ++ks) {
      const short8v a0 = *(const short8v*)&xb[(g * 32 + l15) * 136 + ks * 32 + cb];
      const short8v a1 = *(const short8v*)&xb[(g * 32 + 16 + l15) * 136 + ks * 32 + cb];
#pragma unroll
      for (int mat = 0; mat < 2; ++mat)
#pragma unroll
        for (int nt = 0; nt < 2; ++nt) {
          const short8v bfr =
              *(const short8v*)&wq[(mat * 128 + h * 32 + nt * 16 + l15) * 128 + ks * 32 + cb];
          qk[mat][nt][0] = mfma16(bfr, a0, qk[mat][nt][0]);
          qk[mat][nt][1] = mfma16(bfr, a1, qk[mat][nt][1]);
        }
    }
    const float scale = 0.1767766952966369f;  // 32^-0.5
#pragma unroll
    for (int jt = 0; jt < 2; ++jt) {
      short8v qv;
#pragma unroll
      for (int nt = 0; nt < 2; ++nt)
#pragma unroll
        for (int r = 0; r < 4; ++r)
          qv[nt * 4 + r] = f2bf(qk[0][nt][jt][r] * scale);
      qfr[jt] = qv;
    }
#pragma unroll
    for (int jt = 0; jt < 2; ++jt)
#pragma unroll
      for (int nt = 0; nt < 2; ++nt)
#pragma unroll
        for (int r = 0; r < 4; ++r)
          ksm[h * 2304 + (g * 32 + jt * 16 + l15) * 36 + nt * 16 + lhi * 4 + r] =
              f2bf(qk[1][nt][jt][r]);
  }

  // ---- Phase 1b: V projection (normal orientation), store transposed.
  {
    f32x4 av[2][2];      // [nt][mt]
#pragma unroll
    for (int nt = 0; nt < 2; ++nt) {
      const float vb = qkv_b[256 + h * 32 + nt * 16 + l15];
      av[nt][0] = f32x4{vb, vb, vb, vb};
      av[nt][1] = av[nt][0];
    }
#pragma unroll
    for (int ks = 0; ks < 4; ++ks) {
      const short8v a0 = *(const short8v*)&xb[(g * 32 + l15) * 136 + ks * 32 + cb];
      const short8v a1 = *(const short8v*)&xb[(g * 32 + 16 + l15) * 136 + ks * 32 + cb];
#pragma unroll
      for (int nt = 0; nt < 2; ++nt) {
        const short8v bfr =
            *(const short8v*)&wq[(256 + h * 32 + nt * 16 + l15) * 128 + ks * 32 + cb];
        av[nt][0] = mfma16(a0, bfr, av[nt][0]);
        av[nt][1] = mfma16(a1, bfr, av[nt][1]);
      }
    }
    __syncthreads();   // WAR: all waves done reading xb; vtm may overwrite it
#pragma unroll
    for (int nt = 0; nt < 2; ++nt)
#pragma unroll
      for (int mt = 0; mt < 2; ++mt) {
        short4v p;
#pragma unroll
        for (int r = 0; r < 4; ++r) p[r] = f2bf(av[nt][mt][r]);
        *(short4v*)&vtm[(h * 32 + nt * 16 + l15) * 68 + g * 32 + mt * 16 + lhi * 4] = p;
      }
  }
  __syncthreads();

  // ---- Phase 2: S = mfma(K,Q) + cmb; softmax in-lane; swapped PV from regs
  {
    short8v kfr[4];
#pragma unroll
    for (int i = 0; i < 4; ++i) {
      const int ka = h * 2304 + (i * 16 + l15) * 36 + lhi * 4;
      kfr[i] = cat44(*(const short4v*)&ksm[ka], *(const short4v*)&ksm[ka + 16]);
    }
    __syncthreads();   // ksm fully consumed; aom may overwrite it below

    const f32x4* cmb4 = (const f32x4*)cmb;
    const long cbase = (long)(b & 63) * 4096 + h * 1024 + g * 512 + lane;

#pragma unroll
    for (int jt = 0; jt < 2; ++jt) {
      f32x4 s[4];
#pragma unroll
      for (int i = 0; i < 4; ++i)
        s[i] = mfma16(kfr[i], qfr[jt], cmb4[cbase + jt * 256 + i * 64]);

      float mx = s[0][0];
#pragma unroll
      for (int i = 0; i < 4; ++i)
#pragma unroll
        for (int r = 0; r < 4; ++r) mx = fmaxf(mx, s[i][r]);
      mx = fmaxf(mx, __shfl_xor(mx, 16));
      mx = fmaxf(mx, __shfl_xor(mx, 32));
      float sum = 0.f;
#pragma unroll
      for (int i = 0; i < 4; ++i)
#pragma unroll
        for (int r = 0; r < 4; ++r) {
          float e = __expf(s[i][r] - mx);
          s[i][r] = e;
          sum += e;
        }
      sum += __shfl_xor(sum, 16);
      sum += __shfl_xor(sum, 32);
      const float inv = 1.f / sum;

      short8v pb[2];
#pragma unroll
      for (int ks = 0; ks < 2; ++ks) {
        short8v pv;
#pragma unroll
        for (int e = 0; e < 4; ++e) pv[e]     = f2bf(s[2 * ks][e] * inv);
#pragma unroll
        for (int e = 0; e < 4; ++e) pv[4 + e] = f2bf(s[2 * ks + 1][e] * inv);
        pb[ks] = pv;
      }

#pragma unroll
      for (int dt = 0; dt < 2; ++dt) {
        f32x4 o = {0.f, 0.f, 0.f, 0.f};
#pragma unroll
        for (int ks = 0; ks < 2; ++ks) {
          const int va = (h * 32 + dt * 16 + l15) * 68 + ks * 32 + lhi * 4;
          short8v vfr = cat44(*(const short4v*)&vtm[va], *(const short4v*)&vtm[va + 16]);
          o = mfma16(vfr, pb[ks], o);
        }
        short4v p;
#pragma unroll
        for (int r = 0; r < 4; ++r) p[r] = f2bf(o[r]);
        *(short4v*)&aom[(g * 32 + jt * 16 + l15) * 136 + h * 32 + dt * 16 + lhi * 4] = p;
      }
    }
  }
  __syncthreads();

  // ---- Phase 3: output projection Y = AO @ proj_w^T + proj_b (ks-outer)
  {
    f32x4 po[2][2];      // [nt][mt]
#pragma unroll
    for (int nt = 0; nt < 2; ++nt) {
      const float pbv = proj_b[h * 32 + nt * 16 + l15];
      po[nt][0] = f32x4{pbv, pbv, pbv, pbv};
      po[nt][1] = po[nt][0];
    }
#pragma unroll
    for (int ks = 0; ks < 4; ++ks) {
      const short8v p0 = *(const short8v*)&aom[(g * 32 + l15) * 136 + ks * 32 + cb];
      const short8v p1 = *(const short8v*)&aom[(g * 32 + 16 + l15) * 136 + ks * 32 + cb];
#pragma unroll
      for (int nt = 0; nt < 2; ++nt) {
        const short8v wfr =
            *(const short8v*)&wp[(h * 32 + nt * 16 + l15) * 128 + ks * 32 + cb];
        po[nt][0] = mfma16(p0, wfr, po[nt][0]);
        po[nt][1] = mfma16(p1, wfr, po[nt][1]);
      }
    }
    float* outw = out + (long)b * (49 * 128);
#pragma unroll
    for (int nt = 0; nt < 2; ++nt) {
      const int ncol = h * 32 + nt * 16 + l15;
#pragma unroll
      for (int r = 0; r < 4; ++r) {
        const int m0 = g * 32 + lhi * 4 + r;
        if (m0 < 49) outw[m0 * 128 + ncol] = po[nt][0][r];
        const int m1 = m0 + 16;
        if (m1 < 49) outw[m1 * 128 + ncol] = po[nt][1][r];
      }
    }
  }
}

extern "C" void kernel_launch(void* const* d_in, const int* in_sizes, int n_in,
                              void* d_out, int out_size, void* d_ws, size_t ws_size,
                              hipStream_t stream) {
  const float* x          = (const float*)d_in[0];
  const float* mask       = (const float*)d_in[1];
  const float* qkv_w      = (const float*)d_in[2];
  const float* qkv_b      = (const float*)d_in[3];
  const float* proj_w     = (const float*)d_in[4];
  const float* proj_b     = (const float*)d_in[5];
  const float* bias_table = (const float*)d_in[6];

  short* wq  = (short*)d_ws;                         // 384*128 bf16 (98304 B)
  short* wp  = wq + 49152;                           // 128*128 bf16 (32768 B)
  float* cmb = (float*)((char*)d_ws + 131072);       // 4 MB combined bias+mask

  cvt_weights_kernel<<<dim3(192), dim3(256), 0, stream>>>(qkv_w, proj_w, wq, wp);
  build_cmb_kernel<<<dim3(1024), dim3(256), 0, stream>>>(mask, bias_table, cmb);
  win_attn_kernel<<<dim3(4096), dim3(512), 0, stream>>>(
      x, qkv_b, proj_b, wq, wp, cmb, (float*)d_out);
}

// Round 7
// 156.085 us; speedup vs baseline: 2.4742x; 1.0792x over previous
//
#include <hip/hip_runtime.h>
#include <stdint.h>

typedef float  f32x4   __attribute__((ext_vector_type(4)));
typedef float  float4v __attribute__((ext_vector_type(4)));
typedef short  short4v __attribute__((ext_vector_type(4)));
typedef short  short8v __attribute__((ext_vector_type(8)));
typedef __bf16 bf16x8  __attribute__((ext_vector_type(8)));

static __device__ __forceinline__ short f2bf(float f) {
  unsigned u = __builtin_bit_cast(unsigned, f);
  u += 0x7FFFu + ((u >> 16) & 1u);
  return (short)(u >> 16);
}

static __device__ __forceinline__ f32x4 mfma16(short8v a, short8v b, f32x4 c) {
  return __builtin_amdgcn_mfma_f32_16x16x32_bf16(
      __builtin_bit_cast(bf16x8, a), __builtin_bit_cast(bf16x8, b), c, 0, 0, 0);
}

static __device__ __forceinline__ short8v cat44(short4v a, short4v b) {
  short8v r;
  r[0] = a[0]; r[1] = a[1]; r[2] = a[2]; r[3] = a[3];
  r[4] = b[0]; r[5] = b[1]; r[6] = b[2]; r[7] = b[3];
  return r;
}

// Prelude A: convert qkv_w (384x128) and proj_w (128x128) f32 -> bf16.
__global__ void cvt_weights_kernel(const float* __restrict__ qkv_w,
                                   const float* __restrict__ proj_w,
                                   short* __restrict__ wq, short* __restrict__ wp) {
  int i = blockIdx.x * 256 + threadIdx.x;   // grid = 192 blocks -> 49152
  wq[i] = f2bf(qkv_w[i]);
  if (i < 16384) wp[i] = f2bf(proj_w[i]);
}

// Prelude B: combined bias+mask table laid out as the MFMA S-fragment:
// cmb[w(64)][h(4)][qt(4)][i(4)][lane(64)][r(4)] f32  (4 MB)
// key = i*16 + (lane>>4)*4 + r ; q = qt*16 + (lane&15)
__global__ void build_cmb_kernel(const float* __restrict__ mask,
                                 const float* __restrict__ bias_table,
                                 float* __restrict__ cmb) {
  int id   = blockIdx.x * 256 + threadIdx.x;   // grid = 1024 blocks -> 262144
  int lane = id & 63;
  int i    = (id >> 6) & 3;
  int qt   = (id >> 8) & 3;
  int h    = (id >> 10) & 3;
  int w    = id >> 12;
  int q     = qt * 16 + (lane & 15);
  int kbase = i * 16 + ((lane >> 4) << 2);
  f32x4 v;
#pragma unroll
  for (int r = 0; r < 4; ++r) {
    int key = kbase + r;
    float val;
    if (key >= 49) {
      val = -1e30f;
    } else if (q >= 49) {
      val = 0.f;
    } else {
      int qi = q / 7, qj = q - qi * 7;
      int ki = key / 7, kj = key - ki * 7;
      int ridx = (qi - ki + 6) * 13 + (qj - kj + 6);
      val = bias_table[ridx * 4 + h] + mask[w * 2401 + q * 49 + key];
    }
    v[r] = val;
  }
  ((f32x4*)cmb)[id] = v;
}

// One block = one window (49 tokens padded to 64). 512 threads = 8 waves.
// wave (g,h): g = token half, h = head.
// LDS 35 KiB via lifetime aliasing; separate Q/K/V passes keep peak VGPR low.
//   [0,8704)       xb [64][136] x tile  -> later vtm [4][32][68] (WAR barrier)
//   [8704,17920)   ksm [4][64][36] k    -> later aom [64][136]   (after kfr)
__global__ __launch_bounds__(512, 6)
void win_attn_kernel(const float* __restrict__ x,
                     const float* __restrict__ qkv_b,
                     const float* __restrict__ proj_b,
                     const short* __restrict__ wq,
                     const short* __restrict__ wp,
                     const float* __restrict__ cmb,
                     float* __restrict__ out) {
  __shared__ __align__(16) short smem[17920];
  short* xb  = smem;            // [64][136], phases 0-1
  short* vtm = smem;            // ALIAS xb: [4][32][68], phase 1c+
  short* ksm = smem + 8704;     // [4][64][36]
  short* aom = smem + 8704;     // ALIAS ksm: [64][136], phase 2+

  const int b    = blockIdx.x;
  const int tid  = threadIdx.x;
  const int lane = tid & 63;
  const int wv   = tid >> 6;
  const int h    = wv & 3;
  const int g    = wv >> 2;
  const int l15  = lane & 15;
  const int lhi  = lane >> 4;
  const int cb   = lhi * 8;

  // ---- Phase 0: stage x -> bf16 LDS, zero pad rows 49..63
  {
    short4v z = {0, 0, 0, 0};
    for (int idx = tid; idx < 510; idx += 512)
      *(short4v*)&xb[49 * 136 + idx * 4] = z;
    const float* xw = x + (long)b * (49 * 128);
    for (int idx = tid; idx < 1568; idx += 512) {
      int m  = idx >> 5;
      int c0 = (idx & 31) << 2;
      float4v v = *(const float4v*)&xw[m * 128 + c0];
      short4v s;
      s[0] = f2bf(v[0]); s[1] = f2bf(v[1]); s[2] = f2bf(v[2]); s[3] = f2bf(v[3]);
      *(short4v*)&xb[m * 136 + c0] = s;
    }
  }
  __syncthreads();

  // ---- Phase 1a: Q projection, swapped (acc rows = w-col, cols = token).
  short8v qfr[2];
  {
    f32x4 qa[2][2];   // [nt][jt]
#pragma unroll
    for (int nt = 0; nt < 2; ++nt) {
      const f32x4 bias4 = *(const f32x4*)&qkv_b[h * 32 + nt * 16 + lhi * 4];
      qa[nt][0] = bias4;
      qa[nt][1] = bias4;
    }
#pragma unroll
    for (int ks = 0; ks < 4; ++ks) {
      const short8v a0 = *(const short8v*)&xb[(g * 32 + l15) * 136 + ks * 32 + cb];
      const short8v a1 = *(const short8v*)&xb[(g * 32 + 16 + l15) * 136 + ks * 32 + cb];
#pragma unroll
      for (int nt = 0; nt < 2; ++nt) {
        const short8v bfr =
            *(const short8v*)&wq[(h * 32 + nt * 16 + l15) * 128 + ks * 32 + cb];
        qa[nt][0] = mfma16(bfr, a0, qa[nt][0]);
        qa[nt][1] = mfma16(bfr, a1, qa[nt][1]);
      }
    }
    const float scale = 0.1767766952966369f;  // 32^-0.5
#pragma unroll
    for (int jt = 0; jt < 2; ++jt) {
      short8v qv;
#pragma unroll
      for (int nt = 0; nt < 2; ++nt)
#pragma unroll
        for (int r = 0; r < 4; ++r)
          qv[nt * 4 + r] = f2bf(qa[nt][jt][r] * scale);
      qfr[jt] = qv;
    }
  }

  // ---- Phase 1b: K projection, swapped; store to ksm.
  {
    f32x4 ka[2][2];   // [nt][jt]
#pragma unroll
    for (int nt = 0; nt < 2; ++nt) {
      const f32x4 bias4 = *(const f32x4*)&qkv_b[128 + h * 32 + nt * 16 + lhi * 4];
      ka[nt][0] = bias4;
      ka[nt][1] = bias4;
    }
#pragma unroll
    for (int ks = 0; ks < 4; ++ks) {
      const short8v a0 = *(const short8v*)&xb[(g * 32 + l15) * 136 + ks * 32 + cb];
      const short8v a1 = *(const short8v*)&xb[(g * 32 + 16 + l15) * 136 + ks * 32 + cb];
#pragma unroll
      for (int nt = 0; nt < 2; ++nt) {
        const short8v bfr =
            *(const short8v*)&wq[(128 + h * 32 + nt * 16 + l15) * 128 + ks * 32 + cb];
        ka[nt][0] = mfma16(bfr, a0, ka[nt][0]);
        ka[nt][1] = mfma16(bfr, a1, ka[nt][1]);
      }
    }
#pragma unroll
    for (int jt = 0; jt < 2; ++jt)
#pragma unroll
      for (int nt = 0; nt < 2; ++nt)
#pragma unroll
        for (int r = 0; r < 4; ++r)
          ksm[h * 2304 + (g * 32 + jt * 16 + l15) * 36 + nt * 16 + lhi * 4 + r] =
              f2bf(ka[nt][jt][r]);
  }

  // ---- Phase 1c: V projection (normal orientation), store transposed.
  {
    f32x4 av[2][2];      // [nt][mt]
#pragma unroll
    for (int nt = 0; nt < 2; ++nt) {
      const float vb = qkv_b[256 + h * 32 + nt * 16 + l15];
      av[nt][0] = f32x4{vb, vb, vb, vb};
      av[nt][1] = av[nt][0];
    }
#pragma unroll
    for (int ks = 0; ks < 4; ++ks) {
      const short8v a0 = *(const short8v*)&xb[(g * 32 + l15) * 136 + ks * 32 + cb];
      const short8v a1 = *(const short8v*)&xb[(g * 32 + 16 + l15) * 136 + ks * 32 + cb];
#pragma unroll
      for (int nt = 0; nt < 2; ++nt) {
        const short8v bfr =
            *(const short8v*)&wq[(256 + h * 32 + nt * 16 + l15) * 128 + ks * 32 + cb];
        av[nt][0] = mfma16(a0, bfr, av[nt][0]);
        av[nt][1] = mfma16(a1, bfr, av[nt][1]);
      }
    }
    __syncthreads();   // WAR: all waves done reading xb; vtm may overwrite it
#pragma unroll
    for (int nt = 0; nt < 2; ++nt)
#pragma unroll
      for (int mt = 0; mt < 2; ++mt) {
        short4v p;
#pragma unroll
        for (int r = 0; r < 4; ++r) p[r] = f2bf(av[nt][mt][r]);
        *(short4v*)&vtm[(h * 32 + nt * 16 + l15) * 68 + g * 32 + mt * 16 + lhi * 4] = p;
      }
  }
  __syncthreads();

  // ---- Phase 2: S = mfma(K,Q) + cmb; softmax in-lane; swapped PV from regs
  {
    short8v kfr[4];
#pragma unroll
    for (int i = 0; i < 4; ++i) {
      const int ka = h * 2304 + (i * 16 + l15) * 36 + lhi * 4;
      kfr[i] = cat44(*(const short4v*)&ksm[ka], *(const short4v*)&ksm[ka + 16]);
    }
    __syncthreads();   // ksm fully consumed; aom may overwrite it below

    const f32x4* cmb4 = (const f32x4*)cmb;
    const long cbase = (long)(b & 63) * 4096 + h * 1024 + g * 512 + lane;

#pragma unroll
    for (int jt = 0; jt < 2; ++jt) {
      f32x4 s[4];
#pragma unroll
      for (int i = 0; i < 4; ++i)
        s[i] = mfma16(kfr[i], qfr[jt], cmb4[cbase + jt * 256 + i * 64]);

      float mx = s[0][0];
#pragma unroll
      for (int i = 0; i < 4; ++i)
#pragma unroll
        for (int r = 0; r < 4; ++r) mx = fmaxf(mx, s[i][r]);
      mx = fmaxf(mx, __shfl_xor(mx, 16));
      mx = fmaxf(mx, __shfl_xor(mx, 32));
      float sum = 0.f;
#pragma unroll
      for (int i = 0; i < 4; ++i)
#pragma unroll
        for (int r = 0; r < 4; ++r) {
          float e = __expf(s[i][r] - mx);
          s[i][r] = e;
          sum += e;
        }
      sum += __shfl_xor(sum, 16);
      sum += __shfl_xor(sum, 32);
      const float inv = 1.f / sum;

      short8v pb[2];
#pragma unroll
      for (int ks = 0; ks < 2; ++ks) {
        short8v pv;
#pragma unroll
        for (int e = 0; e < 4; ++e) pv[e]     = f2bf(s[2 * ks][e] * inv);
#pragma unroll
        for (int e = 0; e < 4; ++e) pv[4 + e] = f2bf(s[2 * ks + 1][e] * inv);
        pb[ks] = pv;
      }

#pragma unroll
      for (int dt = 0; dt < 2; ++dt) {
        f32x4 o = {0.f, 0.f, 0.f, 0.f};
#pragma unroll
        for (int ks = 0; ks < 2; ++ks) {
          const int va = (h * 32 + dt * 16 + l15) * 68 + ks * 32 + lhi * 4;
          short8v vfr = cat44(*(const short4v*)&vtm[va], *(const short4v*)&vtm[va + 16]);
          o = mfma16(vfr, pb[ks], o);
        }
        short4v p;
#pragma unroll
        for (int r = 0; r < 4; ++r) p[r] = f2bf(o[r]);
        *(short4v*)&aom[(g * 32 + jt * 16 + l15) * 136 + h * 32 + dt * 16 + lhi * 4] = p;
      }
    }
  }
  __syncthreads();

  // ---- Phase 3: output projection Y = AO @ proj_w^T + proj_b (ks-outer)
  {
    f32x4 po[2][2];      // [nt][mt]
#pragma unroll
    for (int nt = 0; nt < 2; ++nt) {
      const float pbv = proj_b[h * 32 + nt * 16 + l15];
      po[nt][0] = f32x4{pbv, pbv, pbv, pbv};
      po[nt][1] = po[nt][0];
    }
#pragma unroll
    for (int ks = 0; ks < 4; ++ks) {
      const short8v p0 = *(const short8v*)&aom[(g * 32 + l15) * 136 + ks * 32 + cb];
      const short8v p1 = *(const short8v*)&aom[(g * 32 + 16 + l15) * 136 + ks * 32 + cb];
#pragma unroll
      for (int nt = 0; nt < 2; ++nt) {
        const short8v wfr =
            *(const short8v*)&wp[(h * 32 + nt * 16 + l15) * 128 + ks * 32 + cb];
        po[nt][0] = mfma16(p0, wfr, po[nt][0]);
        po[nt][1] = mfma16(p1, wfr, po[nt][1]);
      }
    }
    float* outw = out + (long)b * (49 * 128);
#pragma unroll
    for (int nt = 0; nt < 2; ++nt) {
      const int ncol = h * 32 + nt * 16 + l15;
#pragma unroll
      for (int r = 0; r < 4; ++r) {
        const int m0 = g * 32 + lhi * 4 + r;
        if (m0 < 49) outw[m0 * 128 + ncol] = po[nt][0][r];
        const int m1 = m0 + 16;
        if (m1 < 49) outw[m1 * 128 + ncol] = po[nt][1][r];
      }
    }
  }
}

extern "C" void kernel_launch(void* const* d_in, const int* in_sizes, int n_in,
                              void* d_out, int out_size, void* d_ws, size_t ws_size,
                              hipStream_t stream) {
  const float* x          = (const float*)d_in[0];
  const float* mask       = (const float*)d_in[1];
  const float* qkv_w      = (const float*)d_in[2];
  const float* qkv_b      = (const float*)d_in[3];
  const float* proj_w     = (const float*)d_in[4];
  const float* proj_b     = (const float*)d_in[5];
  const float* bias_table = (const float*)d_in[6];

  short* wq  = (short*)d_ws;                         // 384*128 bf16 (98304 B)
  short* wp  = wq + 49152;                           // 128*128 bf16 (32768 B)
  float* cmb = (float*)((char*)d_ws + 131072);       // 4 MB combined bias+mask

  cvt_weights_kernel<<<dim3(192), dim3(256), 0, stream>>>(qkv_w, proj_w, wq, wp);
  build_cmb_kernel<<<dim3(1024), dim3(256), 0, stream>>>(mask, bias_table, cmb);
  win_attn_kernel<<<dim3(4096), dim3(512), 0, stream>>>(
      x, qkv_b, proj_b, wq, wp, cmb, (float*)d_out);
}